// Round 1
// baseline (323.340 us; speedup 1.0000x reference)
//
#include <hip/hip_runtime.h>

#define SH_DIM 81   // (LMAX+1)^2
#define RB 32       // RES_BETA
#define RA 63       // RES_ALPHA

// Full 64-lane f32 sum via DPP (VALU pipe). Result valid in lane 63.
__device__ __forceinline__ float wave_sum64(float v) {
    v += __int_as_float(__builtin_amdgcn_update_dpp(0, __float_as_int(v), 0x111, 0xf, 0xf, true)); // row_shr:1
    v += __int_as_float(__builtin_amdgcn_update_dpp(0, __float_as_int(v), 0x112, 0xf, 0xf, true)); // row_shr:2
    v += __int_as_float(__builtin_amdgcn_update_dpp(0, __float_as_int(v), 0x114, 0xf, 0xf, true)); // row_shr:4
    v += __int_as_float(__builtin_amdgcn_update_dpp(0, __float_as_int(v), 0x118, 0xf, 0xf, true)); // row_shr:8
    v += __int_as_float(__builtin_amdgcn_update_dpp(0, __float_as_int(v), 0x142, 0xf, 0xf, true)); // row_bcast:15
    v += __int_as_float(__builtin_amdgcn_update_dpp(0, __float_as_int(v), 0x143, 0xf, 0xf, true)); // row_bcast:31
    return v;
}

__global__ __launch_bounds__(256) void gaunt_s2grid_kernel(
    const float* __restrict__ x1, const float* __restrict__ x2,
    const float* __restrict__ shb, const float* __restrict__ sha,
    const float* __restrict__ qw, float* __restrict__ out)
{
    // sha staged [a][i], row-major, 64 rows (row 63 zeroed so lanes a>=63 contribute 0)
    __shared__ float sha_s[64 * SH_DIM];
    __shared__ float part[4 * SH_DIM];

    const int tid = threadIdx.x;
    const int z = blockIdx.x;

    for (int idx = tid; idx < 64 * SH_DIM; idx += 256)
        sha_s[idx] = (idx < RA * SH_DIM) ? sha[idx] : 0.0f;
    __syncthreads();

    const int lane = tid & 63;
    const int w  = __builtin_amdgcn_readfirstlane(tid >> 6); // wave id, provably uniform
    const int b0 = w * 8;

    const float* __restrict__ xz1 = x1 + (size_t)z * SH_DIM;
    const float* __restrict__ xz2 = x2 + (size_t)z * SH_DIM;
    const float* __restrict__ sha_row = sha_s + lane * SH_DIM;

    // ---- Phase B: g1[b,a] = sum_i x1[i]*shb[b,i]*sha[a,i]  (lane = a, 8 b's per wave)
    float g1[8], g2[8];
    #pragma unroll
    for (int bb = 0; bb < 8; ++bb) { g1[bb] = 0.0f; g2[bb] = 0.0f; }

    #pragma unroll 4
    for (int i = 0; i < SH_DIM; ++i) {
        const float sv = sha_row[i];          // per-lane LDS read (2-way alias, free)
        const float t1 = xz1[i] * sv;         // xz1[i] uniform -> s_load
        const float t2 = xz2[i] * sv;
        #pragma unroll
        for (int bb = 0; bb < 8; ++bb) {
            const float h = shb[(b0 + bb) * SH_DIM + i];   // uniform -> s_load
            g1[bb] = fmaf(h, t1, g1[bb]);
            g2[bb] = fmaf(h, t2, g2[bb]);
        }
    }

    // ---- pointwise product on the grid, fold in quadrature weight
    float q[8];
    #pragma unroll
    for (int bb = 0; bb < 8; ++bb)
        q[bb] = g1[bb] * g2[bb] * qw[b0 + bb];             // qw uniform -> s_load

    // ---- Phase C: out[i] = sum_a sha[a,i] * sum_b q[b,a]*shb[b,i]
    #pragma unroll 4
    for (int i = 0; i < SH_DIM; ++i) {
        float t = 0.0f;
        #pragma unroll
        for (int bb = 0; bb < 8; ++bb)
            t = fmaf(q[bb], shb[(b0 + bb) * SH_DIM + i], t);
        float v = t * sha_row[i];
        v = wave_sum64(v);                     // lane 63 holds sum over a
        if (lane == 63) part[w * SH_DIM + i] = v;
    }
    __syncthreads();

    // combine the 4 waves' b-partials and store
    for (int i = tid; i < SH_DIM; i += 256) {
        out[(size_t)z * SH_DIM + i] =
            part[i] + part[SH_DIM + i] + part[2 * SH_DIM + i] + part[3 * SH_DIM + i];
    }
}

extern "C" void kernel_launch(void* const* d_in, const int* in_sizes, int n_in,
                              void* d_out, int out_size, void* d_ws, size_t ws_size,
                              hipStream_t stream) {
    const float* x1  = (const float*)d_in[0];
    const float* x2  = (const float*)d_in[1];
    const float* shb = (const float*)d_in[2];
    const float* sha = (const float*)d_in[3];
    const float* qw  = (const float*)d_in[4];
    float* out = (float*)d_out;

    const int Z = in_sizes[0] / SH_DIM;   // 16384
    gaunt_s2grid_kernel<<<Z, 256, 0, stream>>>(x1, x2, shb, sha, qw, out);
}

// Round 2
// 74.496 us; speedup vs baseline: 4.3404x; 4.3404x over previous
//
#include <hip/hip_runtime.h>

#define DIM 81     // (LMAX+1)^2
#define KP  96     // DIM padded to 3*32
#define RB  32
#define RA  63
#define NBA 2016   // RB*RA
#define ZT  64     // z rows per block
#define XP_STRIDE 104   // f16 elems, padded (bank spread)
#define P_STRIDE  40    // f16 elems, padded
#define RED_STRIDE 100  // f32 elems

typedef _Float16 half8 __attribute__((ext_vector_type(8)));
typedef float floatx4 __attribute__((ext_vector_type(4)));

// ---------------- W precompute: W1[ba][k], W2T[k][ba] (qw folded) ----------------
__global__ __launch_bounds__(256) void precompute_w(
    const float* __restrict__ shb, const float* __restrict__ sha,
    const float* __restrict__ qw,
    _Float16* __restrict__ W1, _Float16* __restrict__ W2T)
{
    int idx = blockIdx.x * 256 + threadIdx.x;
    if (idx >= NBA * KP) return;
    int ba = idx / KP;
    int k  = idx - ba * KP;
    int b  = ba / RA;
    int a  = ba - b * RA;
    float w1 = 0.f, w2 = 0.f;
    if (k < DIM) {
        float v = shb[b * DIM + k] * sha[a * DIM + k];
        w1 = v;
        w2 = v * qw[b];
    }
    W1[(size_t)ba * KP + k]  = (_Float16)w1;   // zero-padded K: required
    W2T[(size_t)k * NBA + ba] = (_Float16)w2;
}

// ---------------- main fused MFMA kernel ----------------
__global__ __launch_bounds__(256, 1) void gaunt_mfma_kernel(
    const float* __restrict__ x1, const float* __restrict__ x2,
    const _Float16* __restrict__ W1, const _Float16* __restrict__ W2T,
    float* __restrict__ out)
{
    __shared__ __align__(16) char lds[36864];
    _Float16* xp = (_Float16*)lds;               // [2][ZT][XP_STRIDE]

    const int tid = threadIdx.x;
    const int z0  = blockIdx.x * ZT;

    // stage X1,X2 -> f16 LDS (cols 81..95 zero)
    #pragma unroll
    for (int in = 0; in < 2; ++in) {
        const float* src = in ? x2 : x1;
        _Float16* dst = xp + in * (ZT * XP_STRIDE);
        for (int idx = tid; idx < ZT * KP; idx += 256) {
            int row = idx / KP, col = idx - row * KP;
            float v = (col < DIM) ? src[(size_t)(z0 + row) * DIM + col] : 0.f;
            dst[row * XP_STRIDE + col] = (_Float16)v;
        }
    }
    __syncthreads();

    const int lane = tid & 63;
    const int w    = tid >> 6;
    const int m2   = w & 1;    // z-half: rows m2*32 .. +32
    const int pw   = w >> 1;   // ba-tile parity
    const int l15  = lane & 15;
    const int lg   = lane >> 4;

    // A-frags (X) from LDS, held in VGPR for the whole kernel: [in][s][k]
    half8 afr[2][2][3];
    #pragma unroll
    for (int in = 0; in < 2; ++in)
      #pragma unroll
      for (int s = 0; s < 2; ++s) {
        const int zr = m2 * 32 + s * 16 + l15;
        const _Float16* base = xp + in * (ZT * XP_STRIDE) + zr * XP_STRIDE + lg * 8;
        #pragma unroll
        for (int k = 0; k < 3; ++k)
            afr[in][s][k] = *(const half8*)(base + k * 32);
      }

    _Float16* pbuf = (_Float16*)(lds + 26624 + w * 2560);  // wave-private P [32][P_STRIDE]

    floatx4 accO[2][6];
    #pragma unroll
    for (int s = 0; s < 2; ++s)
      #pragma unroll
      for (int n = 0; n < 6; ++n)
        accO[s][n] = (floatx4){0.f, 0.f, 0.f, 0.f};

    for (int nb = pw; nb < 63; nb += 2) {
        const int ba0 = nb * 32;

        // ---- GEMM1: G[z, ba] tiles, A = X (VGPR), B = W1 (global/L1)
        floatx4 aG[2][2][2];   // [in][s][t]
        #pragma unroll
        for (int in = 0; in < 2; ++in)
          #pragma unroll
          for (int s = 0; s < 2; ++s)
            #pragma unroll
            for (int t = 0; t < 2; ++t)
                aG[in][s][t] = (floatx4){0.f, 0.f, 0.f, 0.f};

        #pragma unroll
        for (int t = 0; t < 2; ++t)
          #pragma unroll
          for (int k = 0; k < 3; ++k) {
            const half8 bfr = *(const half8*)(W1 + (size_t)(ba0 + t * 16 + l15) * KP + k * 32 + lg * 8);
            #pragma unroll
            for (int in = 0; in < 2; ++in)
              #pragma unroll
              for (int s = 0; s < 2; ++s)
                aG[in][s][t] = __builtin_amdgcn_mfma_f32_16x16x32_f16(
                                   afr[in][s][k], bfr, aG[in][s][t], 0, 0, 0);
          }

        // ---- P = G1*G2 -> f16 -> wave-private LDS (C layout: col=l15, row=lg*4+r)
        #pragma unroll
        for (int s = 0; s < 2; ++s)
          #pragma unroll
          for (int t = 0; t < 2; ++t)
            #pragma unroll
            for (int r = 0; r < 4; ++r) {
                float p = aG[0][s][t][r] * aG[1][s][t][r];
                pbuf[(s * 16 + lg * 4 + r) * P_STRIDE + t * 16 + l15] = (_Float16)p;
            }

        // ---- GEMM2: OUT[z, i] += P * W2T, A = P (LDS), B = W2T (global/L1)
        half8 aP[2];
        #pragma unroll
        for (int s = 0; s < 2; ++s)
            aP[s] = *(const half8*)(pbuf + (s * 16 + l15) * P_STRIDE + lg * 8);

        #pragma unroll
        for (int n = 0; n < 6; ++n) {
            const half8 bfr = *(const half8*)(W2T + (size_t)(n * 16 + l15) * NBA + ba0 + lg * 8);
            #pragma unroll
            for (int s = 0; s < 2; ++s)
                accO[s][n] = __builtin_amdgcn_mfma_f32_16x16x32_f16(
                                 aP[s], bfr, accO[s][n], 0, 0, 0);
        }
    }

    // ---- cross-parity reduction (waves 2,3 -> LDS; waves 0,1 add + store)
    float* red = (float*)lds;   // reuse xp region: [2][32][RED_STRIDE] = 25600 B
    if (w >= 2) {
        #pragma unroll
        for (int s = 0; s < 2; ++s)
          #pragma unroll
          for (int n = 0; n < 6; ++n)
            #pragma unroll
            for (int r = 0; r < 4; ++r)
                red[m2 * 3200 + (s * 16 + lg * 4 + r) * RED_STRIDE + n * 16 + l15] = accO[s][n][r];
    }
    __syncthreads();
    if (w < 2) {
        #pragma unroll
        for (int s = 0; s < 2; ++s)
          #pragma unroll
          for (int n = 0; n < 6; ++n) {
            const int i = n * 16 + l15;
            if (i < DIM) {
              #pragma unroll
              for (int r = 0; r < 4; ++r) {
                const int zloc = s * 16 + lg * 4 + r;
                out[(size_t)(z0 + m2 * 32 + zloc) * DIM + i] =
                    accO[s][n][r] + red[m2 * 3200 + zloc * RED_STRIDE + i];
              }
            }
          }
    }
}

// ---------------- fp32 fallback (round-1 kernel), used only if ws too small ----------------
__device__ __forceinline__ float wave_sum64(float v) {
    v += __int_as_float(__builtin_amdgcn_update_dpp(0, __float_as_int(v), 0x111, 0xf, 0xf, true));
    v += __int_as_float(__builtin_amdgcn_update_dpp(0, __float_as_int(v), 0x112, 0xf, 0xf, true));
    v += __int_as_float(__builtin_amdgcn_update_dpp(0, __float_as_int(v), 0x114, 0xf, 0xf, true));
    v += __int_as_float(__builtin_amdgcn_update_dpp(0, __float_as_int(v), 0x118, 0xf, 0xf, true));
    v += __int_as_float(__builtin_amdgcn_update_dpp(0, __float_as_int(v), 0x142, 0xf, 0xf, true));
    v += __int_as_float(__builtin_amdgcn_update_dpp(0, __float_as_int(v), 0x143, 0xf, 0xf, true));
    return v;
}

__global__ __launch_bounds__(256) void gaunt_s2grid_kernel(
    const float* __restrict__ x1, const float* __restrict__ x2,
    const float* __restrict__ shb, const float* __restrict__ sha,
    const float* __restrict__ qw, float* __restrict__ out)
{
    __shared__ float sha_s[64 * DIM];
    __shared__ float part[4 * DIM];
    const int tid = threadIdx.x;
    const int z = blockIdx.x;
    for (int idx = tid; idx < 64 * DIM; idx += 256)
        sha_s[idx] = (idx < RA * DIM) ? sha[idx] : 0.0f;
    __syncthreads();
    const int lane = tid & 63;
    const int w = __builtin_amdgcn_readfirstlane(tid >> 6);
    const int b0 = w * 8;
    const float* xz1 = x1 + (size_t)z * DIM;
    const float* xz2 = x2 + (size_t)z * DIM;
    const float* sha_row = sha_s + lane * DIM;
    float g1[8], g2[8];
    #pragma unroll
    for (int bb = 0; bb < 8; ++bb) { g1[bb] = 0.0f; g2[bb] = 0.0f; }
    #pragma unroll 4
    for (int i = 0; i < DIM; ++i) {
        const float sv = sha_row[i];
        const float t1 = xz1[i] * sv, t2 = xz2[i] * sv;
        #pragma unroll
        for (int bb = 0; bb < 8; ++bb) {
            const float h = shb[(b0 + bb) * DIM + i];
            g1[bb] = fmaf(h, t1, g1[bb]);
            g2[bb] = fmaf(h, t2, g2[bb]);
        }
    }
    float q[8];
    #pragma unroll
    for (int bb = 0; bb < 8; ++bb) q[bb] = g1[bb] * g2[bb] * qw[b0 + bb];
    #pragma unroll 4
    for (int i = 0; i < DIM; ++i) {
        float t = 0.0f;
        #pragma unroll
        for (int bb = 0; bb < 8; ++bb) t = fmaf(q[bb], shb[(b0 + bb) * DIM + i], t);
        float v = wave_sum64(t * sha_row[i]);
        if (lane == 63) part[w * DIM + i] = v;
    }
    __syncthreads();
    for (int i = tid; i < DIM; i += 256)
        out[(size_t)z * DIM + i] = part[i] + part[DIM + i] + part[2 * DIM + i] + part[3 * DIM + i];
}

extern "C" void kernel_launch(void* const* d_in, const int* in_sizes, int n_in,
                              void* d_out, int out_size, void* d_ws, size_t ws_size,
                              hipStream_t stream) {
    const float* x1  = (const float*)d_in[0];
    const float* x2  = (const float*)d_in[1];
    const float* shb = (const float*)d_in[2];
    const float* sha = (const float*)d_in[3];
    const float* qw  = (const float*)d_in[4];
    float* out = (float*)d_out;

    const int Z = in_sizes[0] / DIM;                 // 16384
    const size_t wbytes = (size_t)NBA * KP * 2 * 2;  // 774144

    if (ws_size >= wbytes && (Z % ZT) == 0) {
        _Float16* W1  = (_Float16*)d_ws;
        _Float16* W2T = W1 + (size_t)NBA * KP;
        precompute_w<<<(NBA * KP + 255) / 256, 256, 0, stream>>>(shb, sha, qw, W1, W2T);
        gaunt_mfma_kernel<<<Z / ZT, 256, 0, stream>>>(x1, x2, W1, W2T, out);
    } else {
        gaunt_s2grid_kernel<<<Z, 256, 0, stream>>>(x1, x2, shb, sha, qw, out);
    }
}

// Round 4
// 50.046 us; speedup vs baseline: 6.4608x; 1.4885x over previous
//
#include <hip/hip_runtime.h>

#define DIM 81     // (LMAX+1)^2
#define KP  96     // DIM padded to 6*16
#define RA  63
#define NBA 2016
#define NBAP 2048  // padded ba (zeros beyond 2016)
#define ZT  64     // z rows per block
#define XS  104    // X LDS stride (halves), 16B-aligned rows, 4-way bank spread
#define OS  97     // out-staging stride (floats), odd -> conflict-free

typedef _Float16 half8 __attribute__((ext_vector_type(8)));
typedef __fp16  fp16x2 __attribute__((ext_vector_type(2)));
typedef float floatx16 __attribute__((ext_vector_type(16)));

union H8U { unsigned u[4]; half8 h; };
union H2U { fp16x2 h; unsigned u; };

// ---------- W precompute: W1[ba 2048][k 96], W2[i 96][ba 2048] (qw folded), zero-padded ----------
__global__ __launch_bounds__(256) void precompute_w(
    const float* __restrict__ shb, const float* __restrict__ sha,
    const float* __restrict__ qw,
    _Float16* __restrict__ W1, _Float16* __restrict__ W2)
{
    int idx = blockIdx.x * 256 + threadIdx.x;
    if (idx >= NBAP * KP) return;
    int ba = idx / KP, k = idx - ba * KP;
    float w1 = 0.f, w2 = 0.f;
    if (ba < NBA && k < DIM) {
        int b = ba / RA, a = ba - b * RA;
        float v = shb[b * DIM + k] * sha[a * DIM + k];
        w1 = v;
        w2 = v * qw[b];
    }
    W1[(size_t)ba * KP + k]  = (_Float16)w1;
    W2[(size_t)k * NBAP + ba] = (_Float16)w2;
}

// ---------- main kernel: swapped-operand MFMA, register-resident P ----------
__global__ __launch_bounds__(512, 2) void gaunt_mfma2(
    const float* __restrict__ x1, const float* __restrict__ x2,
    const _Float16* __restrict__ W1, const _Float16* __restrict__ W2,
    float* __restrict__ out)
{
    __shared__ __align__(16) char lds[26624];
    _Float16* xp = (_Float16*)lds;          // [2][ZT][XS] f16
    float*    ob = (float*)lds;             // [ZT][OS] f32 (reused after main loop)

    const int tid = threadIdx.x;
    const int z0  = blockIdx.x * ZT;

    // stage X1,X2 -> f16 LDS
    #pragma unroll
    for (int in = 0; in < 2; ++in) {
        const float* src = in ? x2 : x1;
        _Float16* dst = xp + in * (ZT * XS);
        for (int idx = tid; idx < ZT * KP; idx += 512) {
            int r = idx / KP, c = idx - r * KP;
            float v = (c < DIM) ? src[(size_t)(z0 + r) * DIM + c] : 0.f;
            dst[r * XS + c] = (_Float16)v;
        }
    }
    __syncthreads();

    const int l = tid & 63, l31 = l & 31, hi = l >> 5;
    const int zg = (tid >> 6) & 1;   // z-group: rows zg*32..+32
    const int nw = tid >> 7;         // ba-quarter within each 256-wide phase pair

    // X fragments (B-operand: col=z=l31, k=hi*8+j), register-resident for whole kernel
    half8 xfr[2][6];
    #pragma unroll
    for (int in = 0; in < 2; ++in)
        #pragma unroll
        for (int kk = 0; kk < 6; ++kk)
            xfr[in][kk] = *(const half8*)(xp + in * (ZT * XS) + (zg * 32 + l31) * XS + kk * 16 + hi * 8);

    floatx16 accO[3];
    #pragma unroll
    for (int m = 0; m < 3; ++m)
        #pragma unroll
        for (int r = 0; r < 16; ++r) accO[m][r] = 0.f;

    const _Float16* w1lane = W1 + (size_t)l31 * KP + (size_t)hi * 8;
    const _Float16* w2lane = W2 + (size_t)l31 * NBAP + (size_t)hi * 8;

    // phase p: ba = (p>>1)*256 + nw*64 + (p&1)*32
    half8 w1c[6];
    {
        const _Float16* pw1 = w1lane + (size_t)(nw * 64) * KP;
        #pragma unroll
        for (int kk = 0; kk < 6; ++kk) w1c[kk] = *(const half8*)(pw1 + kk * 16);
    }

    for (int p = 0; p < 16; ++p) {
        const int ba = (p >> 1) * 256 + nw * 64 + (p & 1) * 32;

        // W2 A-frags for this phase (consumed after GEMM1 -> latency hidden)
        half8 w2f[6];
        {
            const _Float16* pw2 = w2lane + ba;
            #pragma unroll
            for (int mr2 = 0; mr2 < 3; ++mr2) {
                w2f[mr2 * 2]     = *(const half8*)(pw2 + (size_t)mr2 * 32 * NBAP);
                w2f[mr2 * 2 + 1] = *(const half8*)(pw2 + (size_t)mr2 * 32 * NBAP + 16);
            }
        }
        // prefetch next phase's W1 A-frags
        half8 w1n[6];
        {
            const int pn = (p + 1 < 16) ? p + 1 : 15;
            const int bn = (pn >> 1) * 256 + nw * 64 + (pn & 1) * 32;
            const _Float16* pw1 = w1lane + (size_t)bn * KP;
            #pragma unroll
            for (int kk = 0; kk < 6; ++kk) w1n[kk] = *(const half8*)(pw1 + kk * 16);
        }

        // GEMM1 (swapped): Gt[ba 32][z 32] = W1 * X^T, for both inputs
        floatx16 g0, g1;
        #pragma unroll
        for (int r = 0; r < 16; ++r) { g0[r] = 0.f; g1[r] = 0.f; }
        #pragma unroll
        for (int kk = 0; kk < 6; ++kk) {
            g0 = __builtin_amdgcn_mfma_f32_32x32x16_f16(w1c[kk], xfr[0][kk], g0, 0, 0, 0);
            g1 = __builtin_amdgcn_mfma_f32_32x32x16_f16(w1c[kk], xfr[1][kk], g1, 0, 0, 0);
        }

        // P = G1*G2 -> f16 packed; assemble GEMM2 B-frags in-register via permlane32_swap
        unsigned q[8];
        #pragma unroll
        for (int j = 0; j < 8; ++j) {
            H2U t;
            t.h = __builtin_amdgcn_cvt_pkrtz(g0[2 * j] * g1[2 * j], g0[2 * j + 1] * g1[2 * j + 1]);
            q[j] = t.u;
        }
        asm volatile("v_permlane32_swap_b32 %0, %1" : "+v"(q[0]), "+v"(q[2]));
        asm volatile("v_permlane32_swap_b32 %0, %1" : "+v"(q[1]), "+v"(q[3]));
        asm volatile("v_permlane32_swap_b32 %0, %1" : "+v"(q[4]), "+v"(q[6]));
        asm volatile("v_permlane32_swap_b32 %0, %1" : "+v"(q[5]), "+v"(q[7]));
        H8U f0, f1;
        f0.u[0] = q[0]; f0.u[1] = q[1]; f0.u[2] = q[2]; f0.u[3] = q[3];
        f1.u[0] = q[4]; f1.u[1] = q[5]; f1.u[2] = q[6]; f1.u[3] = q[7];

        // GEMM2: OUTt[i 96][z 32] += W2 * P  (k = ba, 2 k-steps of 16)
        #pragma unroll
        for (int mr2 = 0; mr2 < 3; ++mr2) {
            accO[mr2] = __builtin_amdgcn_mfma_f32_32x32x16_f16(w2f[mr2 * 2],     f0.h, accO[mr2], 0, 0, 0);
            accO[mr2] = __builtin_amdgcn_mfma_f32_32x32x16_f16(w2f[mr2 * 2 + 1], f1.h, accO[mr2], 0, 0, 0);
        }

        #pragma unroll
        for (int kk = 0; kk < 6; ++kk) w1c[kk] = w1n[kk];
    }

    // cross-nw reduction: sequential rounds into ob[z][i] (ob aliases xp; first
    // barrier below guarantees every thread is past its xp reads)
    for (int round = 0; round < 4; ++round) {
        __syncthreads();
        if (nw == round) {
            #pragma unroll
            for (int mr2 = 0; mr2 < 3; ++mr2)
                #pragma unroll
                for (int r = 0; r < 16; ++r) {
                    int iloc = mr2 * 32 + (r & 3) + 8 * (r >> 2) + 4 * hi;
                    int zz = zg * 32 + l31;
                    float v = accO[mr2][r];
                    if (round) v += ob[zz * OS + iloc];
                    ob[zz * OS + iloc] = v;
                }
        }
    }
    __syncthreads();

    // coalesced store
    for (int idx = tid; idx < ZT * DIM; idx += 512) {
        int zz = idx / DIM, ii = idx - zz * DIM;
        out[(size_t)z0 * DIM + idx] = ob[zz * OS + ii];
    }
}

// ---------------- fp32 fallback (round-1 kernel; needs no workspace) ----------------
__device__ __forceinline__ float wave_sum64(float v) {
    v += __int_as_float(__builtin_amdgcn_update_dpp(0, __float_as_int(v), 0x111, 0xf, 0xf, true));
    v += __int_as_float(__builtin_amdgcn_update_dpp(0, __float_as_int(v), 0x112, 0xf, 0xf, true));
    v += __int_as_float(__builtin_amdgcn_update_dpp(0, __float_as_int(v), 0x114, 0xf, 0xf, true));
    v += __int_as_float(__builtin_amdgcn_update_dpp(0, __float_as_int(v), 0x118, 0xf, 0xf, true));
    v += __int_as_float(__builtin_amdgcn_update_dpp(0, __float_as_int(v), 0x142, 0xf, 0xf, true));
    v += __int_as_float(__builtin_amdgcn_update_dpp(0, __float_as_int(v), 0x143, 0xf, 0xf, true));
    return v;
}

__global__ __launch_bounds__(256) void gaunt_s2grid_kernel(
    const float* __restrict__ x1, const float* __restrict__ x2,
    const float* __restrict__ shb, const float* __restrict__ sha,
    const float* __restrict__ qw, float* __restrict__ out)
{
    __shared__ float sha_s[64 * DIM];
    __shared__ float part[4 * DIM];
    const int tid = threadIdx.x;
    const int z = blockIdx.x;
    for (int idx = tid; idx < 64 * DIM; idx += 256)
        sha_s[idx] = (idx < RA * DIM) ? sha[idx] : 0.0f;
    __syncthreads();
    const int lane = tid & 63;
    const int w = __builtin_amdgcn_readfirstlane(tid >> 6);
    const int b0 = w * 8;
    const float* xz1 = x1 + (size_t)z * DIM;
    const float* xz2 = x2 + (size_t)z * DIM;
    const float* sha_row = sha_s + lane * DIM;
    float g1[8], g2[8];
    #pragma unroll
    for (int bb = 0; bb < 8; ++bb) { g1[bb] = 0.0f; g2[bb] = 0.0f; }
    #pragma unroll 4
    for (int i = 0; i < DIM; ++i) {
        const float sv = sha_row[i];
        const float t1 = xz1[i] * sv, t2 = xz2[i] * sv;
        #pragma unroll
        for (int bb = 0; bb < 8; ++bb) {
            const float h = shb[(b0 + bb) * DIM + i];
            g1[bb] = fmaf(h, t1, g1[bb]);
            g2[bb] = fmaf(h, t2, g2[bb]);
        }
    }
    float q[8];
    #pragma unroll
    for (int bb = 0; bb < 8; ++bb) q[bb] = g1[bb] * g2[bb] * qw[b0 + bb];
    #pragma unroll 4
    for (int i = 0; i < DIM; ++i) {
        float t = 0.0f;
        #pragma unroll
        for (int bb = 0; bb < 8; ++bb) t = fmaf(q[bb], shb[(b0 + bb) * DIM + i], t);
        float v = wave_sum64(t * sha_row[i]);
        if (lane == 63) part[w * DIM + i] = v;
    }
    __syncthreads();
    for (int i = tid; i < DIM; i += 256)
        out[(size_t)z * DIM + i] = part[i] + part[DIM + i] + part[2 * DIM + i] + part[3 * DIM + i];
}

extern "C" void kernel_launch(void* const* d_in, const int* in_sizes, int n_in,
                              void* d_out, int out_size, void* d_ws, size_t ws_size,
                              hipStream_t stream) {
    const float* x1  = (const float*)d_in[0];
    const float* x2  = (const float*)d_in[1];
    const float* shb = (const float*)d_in[2];
    const float* sha = (const float*)d_in[3];
    const float* qw  = (const float*)d_in[4];
    float* out = (float*)d_out;

    const int Z = in_sizes[0] / DIM;                    // 16384
    const size_t wbytes = (size_t)NBAP * KP * 2 * 2;    // 786432

    if (ws_size >= wbytes && (Z % ZT) == 0) {
        _Float16* W1 = (_Float16*)d_ws;
        _Float16* W2 = W1 + (size_t)NBAP * KP;
        precompute_w<<<(NBAP * KP + 255) / 256, 256, 0, stream>>>(shb, sha, qw, W1, W2);
        gaunt_mfma2<<<Z / ZT, 512, 0, stream>>>(x1, x2, W1, W2, out);
    } else {
        gaunt_s2grid_kernel<<<Z, 256, 0, stream>>>(x1, x2, shb, sha, qw, out);
    }
}